// Round 7
// baseline (635.745 us; speedup 1.0000x reference)
//
#include <hip/hip_runtime.h>

typedef __bf16 bf16;
typedef bf16 bf16x8 __attribute__((ext_vector_type(8)));
typedef float f32x4 __attribute__((ext_vector_type(4)));
typedef unsigned int uint;
typedef uint u32x4 __attribute__((ext_vector_type(4)));
typedef unsigned short u16x8 __attribute__((ext_vector_type(8)));

constexpr int NT = 4096;   // sequence length N
// H = 64, B = 2

__device__ __forceinline__ bf16x8 ld8f(const float* p) {
    f32x4 a = *(const f32x4*)p;
    f32x4 b = *(const f32x4*)(p + 4);
    bf16x8 v;
    v[0] = (bf16)a[0]; v[1] = (bf16)a[1]; v[2] = (bf16)a[2]; v[3] = (bf16)a[3];
    v[4] = (bf16)b[0]; v[5] = (bf16)b[1]; v[6] = (bf16)b[2]; v[7] = (bf16)b[3];
    return v;
}

__device__ __forceinline__ uint pack2(float a, float b) {
    unsigned short ua = __builtin_bit_cast(unsigned short, (bf16)a);
    unsigned short ub = __builtin_bit_cast(unsigned short, (bf16)b);
    return (uint)ua | ((uint)ub << 16);
}

// ---------------------------------------------------------------------------
// Kernel 1: projections q_t = norm(h_t @ Wq[t]^T), k_e = norm(h_pred @ Wk[e]^T)
// (bf16 out), plus vT[p][b][h][n] = bf16 transpose of h_p.
// grid = 128 rowtiles x 3 slices.
// ---------------------------------------------------------------------------
__global__ __launch_bounds__(256) void prep_kernel(
    const float* __restrict__ h0, const float* __restrict__ h1, const float* __restrict__ h2,
    const float* __restrict__ Wq, const float* __restrict__ Wk,
    bf16* __restrict__ qn, bf16* __restrict__ kn, bf16* __restrict__ vT)
{
    __shared__ __align__(16) unsigned short tlds[4][16][72];
    const int tid = threadIdx.x, wid = tid >> 6, lane = tid & 63;
    const int l15 = lane & 15, quad = lane >> 4;
    const int bx = blockIdx.x;
    const int rt = bx & 127, sl = bx >> 7;       // slice 0..2
    const int g0 = rt * 64;
    const int grow = g0 + wid * 16 + l15;        // A-frag row (global b*N+n)
    const float* hs[3] = {h0, h1, h2};

    bf16x8 af[3][2];
#pragma unroll
    for (int p = 0; p < 3; p++)
#pragma unroll
        for (int hc = 0; hc < 2; hc++)
            af[p][hc] = ld8f(hs[p] + (size_t)grow * 64 + hc * 32 + quad * 8);

    if (sl == 0) {
        const int gr0 = g0 + wid * 16;
        const int bb = gr0 >> 12, n0 = gr0 & 4095;
#pragma unroll
        for (int p = 0; p < 3; p++) {
#pragma unroll
            for (int hc = 0; hc < 2; hc++)
                *(u16x8*)(&tlds[wid][l15][hc * 32 + quad * 8]) = __builtin_bit_cast(u16x8, af[p][hc]);
            unsigned short vals[16];
#pragma unroll
            for (int r = 0; r < 16; r++) vals[r] = tlds[wid][r][lane];
            uint us[8];
#pragma unroll
            for (int k = 0; k < 8; k++) us[k] = (uint)vals[2 * k] | ((uint)vals[2 * k + 1] << 16);
            uint* dst = (uint*)(vT + ((size_t)(p * 2 + bb) * 64 + lane) * NT + n0);
            u32x4 w0 = {us[0], us[1], us[2], us[3]};
            u32x4 w1 = {us[4], us[5], us[6], us[7]};
            *(u32x4*)dst = w0;
            *(u32x4*)(dst + 4) = w1;
        }
    }

    const int predmap[6] = {0, 2, 0, 1, 1, 2};
    const int pj0 = sl * 3;
#pragma unroll
    for (int pi = 0; pi < 3; pi++) {
        const int pj = pj0 + pi;
        const float* W = (pj < 3) ? (Wq + pj * 4096) : (Wk + (pj - 3) * 4096);
        const int src = (pj < 3) ? pj : predmap[pj - 3];
        bf16* outp = (pj < 3) ? (qn + (size_t)pj * 2 * NT * 64)
                              : (kn + (size_t)(pj - 3) * 2 * NT * 64);
        f32x4 s[4];
#pragma unroll
        for (int it = 0; it < 4; it++) {
            f32x4 acc = {0.f, 0.f, 0.f, 0.f};
#pragma unroll
            for (int hc = 0; hc < 2; hc++) {
                bf16x8 wb = ld8f(W + (size_t)(it * 16 + l15) * 64 + hc * 32 + quad * 8);
                acc = __builtin_amdgcn_mfma_f32_16x16x32_bf16(af[src][hc], wb, acc, 0, 0, 0);
            }
            s[it] = acc;
        }
#pragma unroll
        for (int r = 0; r < 4; r++) {
            float ss = s[0][r] * s[0][r] + s[1][r] * s[1][r] + s[2][r] * s[2][r] + s[3][r] * s[3][r];
            ss += __shfl_xor(ss, 1); ss += __shfl_xor(ss, 2);
            ss += __shfl_xor(ss, 4); ss += __shfl_xor(ss, 8);
            float rn = rsqrtf(ss);
            s[0][r] *= rn; s[1][r] *= rn; s[2][r] *= rn; s[3][r] *= rn;
        }
        const int rowbase = g0 + wid * 16 + quad * 4;
#pragma unroll
        for (int it = 0; it < 4; it++)
#pragma unroll
            for (int r = 0; r < 4; r++)
                outp[(size_t)(rowbase + r) * 64 + it * 16 + l15] = (bf16)s[it][r];
    }
}

// ---------------------------------------------------------------------------
// Kernel 2: masked cosine attention — EXACT round-4 configuration (JC=4,
// fp32 Pacc [chunk][e][b][h][n], launch_bounds(256,3); attn=196us, FETCH 278,
// WRITE 69 — the JC=8/u32-pair combo of rounds 5/6 produced +400 MB R+W from
// an unmodeled mechanism and is abandoned) PLUS one controlled change:
// sched_barrier(0) pins after the prefetch issue groups so the compiler
// cannot sink the loads to their use sites (bandwidth-delay: r4 averaged only
// ~2.6 KB in flight/CU -> loads were being sunk, latency exposed each iter).
// ---------------------------------------------------------------------------
template<int JC>
__global__ __launch_bounds__(256, 3) void attn_kernel(
    const bf16* __restrict__ qn, const bf16* __restrict__ kn, const bf16* __restrict__ vT,
    const float* __restrict__ m00, const float* __restrict__ m20, const float* __restrict__ m01,
    const float* __restrict__ m11, const float* __restrict__ m12, const float* __restrict__ m22,
    float* __restrict__ Pacc, float* __restrict__ rsO)
{
    __shared__ __align__(16) bf16 Klds[2][64][72];
    __shared__ __align__(16) bf16 Vlds[2][64][72];
    const int tid = threadIdx.x, wid = tid >> 6, lane = tid & 63;
    const int l15 = lane & 15, quad = lane >> 4;
    const int bx = blockIdx.x;
    const int e = bx / (32 * JC);
    const int rem = bx % (32 * JC);
    const int qt = rem / JC, jcv = rem % JC;
    const int qrow0 = qt * 128, wstrip = wid * 32;
    const int qtypemap[6] = {0, 0, 1, 1, 2, 2};
    const int predmap[6]  = {0, 2, 0, 1, 1, 2};
    const float* masks[6] = {m00, m20, m01, m11, m12, m22};
    const float* __restrict__ mask = masks[e];
    const int qtv = qtypemap[e], pv = predmap[e];
    constexpr int JSPAN = NT / JC;
    constexpr int NI = JSPAN / 64;
    const int jbeg = jcv * JSPAN;

    // per-thread staging line mapping (4 K lines + 4 V lines per thread)
    int s_b[4], s_jl[4], s_ch[4];
#pragma unroll
    for (int i = 0; i < 4; i++) {
        int u = tid + 256 * i;
        s_b[i] = u >> 9; s_jl[i] = (u >> 3) & 63; s_ch[i] = u & 7;
    }

    // Q fragments (stage-1 B-operand), register resident
    bf16x8 Qf[2][2][2];
#pragma unroll
    for (int b = 0; b < 2; b++)
#pragma unroll
        for (int mt = 0; mt < 2; mt++)
#pragma unroll
            for (int hc = 0; hc < 2; hc++)
                Qf[b][mt][hc] = *(const bf16x8*)(qn +
                    ((size_t)(qtv * 2 + b) * NT + qrow0 + wstrip + mt * 16 + l15) * 64 +
                    hc * 32 + quad * 8);

    f32x4 acc2[2][4][2];   // [b][ht][mt]  (acc^T: row=h, col=query)
#pragma unroll
    for (int b = 0; b < 2; b++)
#pragma unroll
        for (int ht = 0; ht < 4; ht++)
#pragma unroll
            for (int mt = 0; mt < 2; mt++) {
                f32x4 z = {0.f, 0.f, 0.f, 0.f};
                acc2[b][ht][mt] = z;
            }
    float rsl[2] = {0.f, 0.f};

    // ---- preload staging + mask regs for first iteration ----
    u32x4 kreg[4], vreg[4];
#pragma unroll
    for (int i = 0; i < 4; i++) {
        kreg[i] = *(const u32x4*)(kn + ((size_t)(e * 2 + s_b[i]) * NT + jbeg + s_jl[i]) * 64 + s_ch[i] * 8);
        vreg[i] = *(const u32x4*)(vT + ((size_t)(pv * 2 + s_b[i]) * 64 + s_jl[i]) * NT + jbeg + s_ch[i] * 8);
    }
    f32x4 mv[2][4];
#pragma unroll
    for (int mt = 0; mt < 2; mt++)
#pragma unroll
        for (int jt = 0; jt < 4; jt++)
            mv[mt][jt] = *(const f32x4*)(mask +
                (size_t)(qrow0 + wstrip + mt * 16 + l15) * NT + jbeg + jt * 16 + quad * 4);

#pragma unroll 1
    for (int ji = 0; ji < NI; ji++) {
        const int jn = (ji + 1 < NI) ? (jbeg + (ji + 1) * 64) : jbeg;   // next (clamped)

        __syncthreads();                           // prior compute done reading LDS
#pragma unroll
        for (int i = 0; i < 4; i++) {
            *(u32x4*)(&Klds[s_b[i]][s_jl[i]][s_ch[i] * 8]) = kreg[i];
            *(u32x4*)(&Vlds[s_b[i]][s_jl[i]][s_ch[i] * 8]) = vreg[i];
        }
        __syncthreads();                           // staged tile visible

        // issue next iteration's staging loads — pinned so the scheduler
        // cannot sink them; they stay in flight across the compute phase
#pragma unroll
        for (int i = 0; i < 4; i++) {
            kreg[i] = *(const u32x4*)(kn + ((size_t)(e * 2 + s_b[i]) * NT + jn + s_jl[i]) * 64 + s_ch[i] * 8);
            vreg[i] = *(const u32x4*)(vT + ((size_t)(pv * 2 + s_b[i]) * 64 + s_jl[i]) * NT + jn + s_ch[i] * 8);
        }
        __builtin_amdgcn_sched_barrier(0);

        // mask rowsums (current mv)
#pragma unroll
        for (int mt = 0; mt < 2; mt++)
#pragma unroll
            for (int jt = 0; jt < 4; jt++)
                rsl[mt] += mv[mt][jt][0] + mv[mt][jt][1] + mv[mt][jt][2] + mv[mt][jt][3];

        // stage 1 for BOTH batches: S^T tiles, mask, pack bf16 pairs
        uint Pd[2][4][2][2];    // [b][jt][mt][d]
#pragma unroll
        for (int jt = 0; jt < 4; jt++)
#pragma unroll
            for (int b = 0; b < 2; b++)
#pragma unroll
                for (int mt = 0; mt < 2; mt++) {
                    f32x4 sc = {0.f, 0.f, 0.f, 0.f};
#pragma unroll
                    for (int hc = 0; hc < 2; hc++) {
                        bf16x8 a = *(const bf16x8*)(&Klds[b][jt * 16 + l15][hc * 32 + quad * 8]);
                        sc = __builtin_amdgcn_mfma_f32_16x16x32_bf16(a, Qf[b][mt][hc], sc, 0, 0, 0);
                    }
                    sc[0] *= mv[mt][jt][0]; sc[1] *= mv[mt][jt][1];
                    sc[2] *= mv[mt][jt][2]; sc[3] *= mv[mt][jt][3];
                    Pd[b][jt][mt][0] = pack2(sc[0], sc[1]);
                    Pd[b][jt][mt][1] = pack2(sc[2], sc[3]);
                }

        // mv's last use is above — issue next iteration's mask loads now,
        // pinned so they cannot be sunk into next iteration's stage 1
#pragma unroll
        for (int mt = 0; mt < 2; mt++)
#pragma unroll
            for (int jt = 0; jt < 4; jt++)
                mv[mt][jt] = *(const f32x4*)(mask +
                    (size_t)(qrow0 + wstrip + mt * 16 + l15) * NT + jn + jt * 16 + quad * 4);
        __builtin_amdgcn_sched_barrier(0);

        // stage 2 per batch: B-frags via ds_bpermute, then acc^T += VT·P^T
#pragma unroll
        for (int b = 0; b < 2; b++) {
            uint Bf[2][2][4];    // [mt][c][v]
#pragma unroll
            for (int mt = 0; mt < 2; mt++)
#pragma unroll
                for (int c = 0; c < 2; c++)
#pragma unroll
                    for (int v = 0; v < 4; v++) {
                        int srclane = ((((quad & 1) * 2 + (v >> 1)) * 16 + l15) << 2);
                        int lo = __builtin_amdgcn_ds_bpermute(srclane, (int)Pd[b][2 * c][mt][v & 1]);
                        int hi = __builtin_amdgcn_ds_bpermute(srclane, (int)Pd[b][2 * c + 1][mt][v & 1]);
                        Bf[mt][c][v] = (quad & 2) ? (uint)hi : (uint)lo;
                    }
#pragma unroll
            for (int ht = 0; ht < 4; ht++)
#pragma unroll
                for (int c = 0; c < 2; c++) {
                    bf16x8 a = *(const bf16x8*)(&Vlds[b][ht * 16 + l15][c * 32 + quad * 8]);
#pragma unroll
                    for (int mt = 0; mt < 2; mt++) {
                        u32x4 t = {Bf[mt][c][0], Bf[mt][c][1], Bf[mt][c][2], Bf[mt][c][3]};
                        bf16x8 bbv = __builtin_bit_cast(bf16x8, t);
                        acc2[b][ht][mt] =
                            __builtin_amdgcn_mfma_f32_16x16x32_bf16(a, bbv, acc2[b][ht][mt], 0, 0, 0);
                    }
                }
        }
    }

    // coalesced fp32 partial store: Pacc[chunk][e][b][h][n]
    // lane (quad,r) -> h = ht*16+quad*4+r ; lanes l15 -> 16 consecutive n (64B)
#pragma unroll
    for (int b = 0; b < 2; b++)
#pragma unroll
        for (int ht = 0; ht < 4; ht++)
#pragma unroll
            for (int mt = 0; mt < 2; mt++) {
                const int n = qrow0 + wstrip + mt * 16 + l15;
#pragma unroll
                for (int r = 0; r < 4; r++) {
                    const int h = ht * 16 + quad * 4 + r;
                    Pacc[(((size_t)(jcv * 6 + e) * 2 + b) * 64 + h) * NT + n] = acc2[b][ht][mt][r];
                }
            }
    // mask rowsums: quads hold disjoint j segments
#pragma unroll
    for (int mt = 0; mt < 2; mt++) {
        float v = rsl[mt];
        v += __shfl_xor(v, 16);
        v += __shfl_xor(v, 32);
        if (quad == 0)
            rsO[(size_t)(jcv * 6 + e) * NT + qrow0 + wstrip + mt * 16 + l15] = v;
    }
}

// ---------------------------------------------------------------------------
// Kernel 3: combine fp32 partials over JC chunks (acc_t = ΣP/Σrs per edge),
// dt_t = 2*sigmoid(h_t Wdt_t^T + b) - 1, h_tn = h_t + step*dt*u_t, outputs.
// Pacc layout [chunk][e][b][h][n]: reads are lane-coalesced over n.
// grid = 128 rowtiles x 3 types.
// ---------------------------------------------------------------------------
template<int JC>
__global__ __launch_bounds__(256) void update_kernel(
    const float* __restrict__ x0, const float* __restrict__ h0,
    const float* __restrict__ h1, const float* __restrict__ h2,
    const float* __restrict__ Wsu0, const float* __restrict__ Wsu12,
    const float* __restrict__ Wdt, const float* __restrict__ bdt,
    const float* __restrict__ stepp, const float* __restrict__ oscp,
    const float* __restrict__ Pacc, const float* __restrict__ rs,
    float* __restrict__ dout)
{
    const int tid = threadIdx.x, wid = tid >> 6, lane = tid & 63;
    const int l15 = lane & 15, quad = lane >> 4;
    const int bx = blockIdx.x;
    const int rt = bx & 127, t = bx >> 7;
    const int g0 = rt * 64;
    const int grow = g0 + wid * 16 + l15;
    const int n = grow & 4095, bb = grow >> 12;
    const float step = *stepp, osc = *oscp;
    const float* hs[3] = {h0, h1, h2};
    const float* __restrict__ ht_base = hs[t];

    bf16x8 afh[2], afacc[2], afx;
#pragma unroll
    for (int hc = 0; hc < 2; hc++)
        afh[hc] = ld8f(ht_base + (size_t)grow * 64 + hc * 32 + quad * 8);
    if (t == 0) afx = ld8f(x0 + (size_t)grow * 32 + quad * 8);

    float s0 = 0.f, s1 = 0.f;
#pragma unroll
    for (int jc = 0; jc < JC; jc++) {
        s0 += rs[(size_t)(jc * 6 + 2 * t) * NT + n];
        s1 += rs[(size_t)(jc * 6 + 2 * t + 1) * NT + n];
    }
    const float i0 = 1.f / s0, i1 = 1.f / s1;
#pragma unroll
    for (int hc = 0; hc < 2; hc++) {
        float S0[8] = {0,0,0,0,0,0,0,0}, S1[8] = {0,0,0,0,0,0,0,0};
#pragma unroll
        for (int jc = 0; jc < JC; jc++) {
            const float* b0 = Pacc + (((size_t)(jc * 6 + 2 * t) * 2 + bb) * 64) * NT + n;
            const float* b1 = Pacc + (((size_t)(jc * 6 + 2 * t + 1) * 2 + bb) * 64) * NT + n;
#pragma unroll
            for (int j = 0; j < 8; j++) {
                const int h = hc * 32 + quad * 8 + j;
                S0[j] += b0[(size_t)h * NT];
                S1[j] += b1[(size_t)h * NT];
            }
        }
        bf16x8 v;
#pragma unroll
        for (int j = 0; j < 8; j++) v[j] = (bf16)(S0[j] * i0 + S1[j] * i1);
        afacc[hc] = v;
    }

    float bdtv[4];
#pragma unroll
    for (int it = 0; it < 4; it++)
        bdtv[it] = bdt[t * 64 + it * 16 + l15];

#pragma unroll
    for (int it = 0; it < 4; it++) {
        f32x4 z = {0.f, 0.f, 0.f, 0.f};
        f32x4 u = {0.f, 0.f, 0.f, 0.f};
#pragma unroll
        for (int hc = 0; hc < 2; hc++) {
            bf16x8 wb = ld8f(Wdt + (size_t)t * 4096 + (size_t)(it * 16 + l15) * 64 + hc * 32 + quad * 8);
            z = __builtin_amdgcn_mfma_f32_16x16x32_bf16(afh[hc], wb, z, 0, 0, 0);
        }
        if (t == 0) {
            bf16x8 w0 = ld8f(Wsu0 + (size_t)(it * 16 + l15) * 96 + quad * 8);
            u = __builtin_amdgcn_mfma_f32_16x16x32_bf16(afx, w0, u, 0, 0, 0);
#pragma unroll
            for (int kc = 0; kc < 2; kc++) {
                bf16x8 wk = ld8f(Wsu0 + (size_t)(it * 16 + l15) * 96 + 32 + kc * 32 + quad * 8);
                u = __builtin_amdgcn_mfma_f32_16x16x32_bf16(afacc[kc], wk, u, 0, 0, 0);
            }
        } else {
#pragma unroll
            for (int kc = 0; kc < 2; kc++) {
                bf16x8 wk = ld8f(Wsu12 + (size_t)(t - 1) * 4096 + (size_t)(it * 16 + l15) * 64 + kc * 32 + quad * 8);
                u = __builtin_amdgcn_mfma_f32_16x16x32_bf16(afacc[kc], wk, u, 0, 0, 0);
            }
        }
        const int colg = it * 16 + l15;
#pragma unroll
        for (int r = 0; r < 4; r++) {
            int row = g0 + wid * 16 + quad * 4 + r;
            float zz = z[r] + bdtv[it];
            float dtv = 2.f / (1.f + __expf(-zz)) - 1.f;
            float hval = ht_base[(size_t)row * 64 + colg];
            float hn = hval + step * dtv * u[r];
            dout[65536 + (size_t)t * 524288 + (size_t)row * 64 + colg] = hn;
            if (t == 2 && colg < 8)
                dout[(size_t)row * 8 + colg] = osc * hn;
        }
    }
}

extern "C" void kernel_launch(void* const* d_in, const int* in_sizes, int n_in,
                              void* d_out, int out_size, void* d_ws, size_t ws_size,
                              hipStream_t stream) {
    const float* x0   = (const float*)d_in[0];
    const float* h0   = (const float*)d_in[1];
    const float* h1   = (const float*)d_in[2];
    const float* h2   = (const float*)d_in[3];
    const float* m00  = (const float*)d_in[4];
    const float* m20  = (const float*)d_in[5];
    const float* m01  = (const float*)d_in[6];
    const float* m11  = (const float*)d_in[7];
    const float* m12  = (const float*)d_in[8];
    const float* m22  = (const float*)d_in[9];
    const float* Wq   = (const float*)d_in[10];
    const float* Wk   = (const float*)d_in[11];
    const float* Wsu0 = (const float*)d_in[12];
    const float* Wsu12= (const float*)d_in[13];
    const float* Wdt  = (const float*)d_in[14];
    const float* bdt  = (const float*)d_in[15];
    const float* step = (const float*)d_in[16];
    const float* oscl = (const float*)d_in[17];

    // workspace layout (element counts)
    bf16* qn  = (bf16*)d_ws;                    // 3*2*4096*64 = 1,572,864
    bf16* kn  = qn + 1572864;                   // 6*2*4096*64 = 3,145,728
    bf16* vT  = kn + 3145728;                   // 3*2*64*4096 = 1,572,864
    float* Pacc = (float*)(vT + 1572864);       // JC*6*2*64*4096 floats
    // rs follows: JC*6*4096 floats

    // bytes: 12,582,912 + JC*12,582,912 (Pacc) + JC*98,304 (rs)
    auto need = [](size_t jc) { return 12582912 + jc * 12582912 + jc * 98304; };
    const int JC = (ws_size >= need(4)) ? 4 : ((ws_size >= need(2)) ? 2 : 1);

    prep_kernel<<<384, 256, 0, stream>>>(h0, h1, h2, Wq, Wk, qn, kn, vT);

    if (JC == 4) {
        float* rs = Pacc + (size_t)4 * 3145728;
        attn_kernel<4><<<6 * 32 * 4, 256, 0, stream>>>(qn, kn, vT, m00, m20, m01, m11, m12, m22, Pacc, rs);
        update_kernel<4><<<384, 256, 0, stream>>>(x0, h0, h1, h2, Wsu0, Wsu12, Wdt, bdt,
                                                  step, oscl, Pacc, rs, (float*)d_out);
    } else if (JC == 2) {
        float* rs = Pacc + (size_t)2 * 3145728;
        attn_kernel<2><<<6 * 32 * 2, 256, 0, stream>>>(qn, kn, vT, m00, m20, m01, m11, m12, m22, Pacc, rs);
        update_kernel<2><<<384, 256, 0, stream>>>(x0, h0, h1, h2, Wsu0, Wsu12, Wdt, bdt,
                                                  step, oscl, Pacc, rs, (float*)d_out);
    } else {
        float* rs = Pacc + (size_t)1 * 3145728;
        attn_kernel<1><<<6 * 32 * 1, 256, 0, stream>>>(qn, kn, vT, m00, m20, m01, m11, m12, m22, Pacc, rs);
        update_kernel<1><<<384, 256, 0, stream>>>(x0, h0, h1, h2, Wsu0, Wsu12, Wdt, bdt,
                                                  step, oscl, Pacc, rs, (float*)d_out);
    }
}

// Round 8
// 519.201 us; speedup vs baseline: 1.2245x; 1.2245x over previous
//
#include <hip/hip_runtime.h>

typedef __bf16 bf16;
typedef bf16 bf16x8 __attribute__((ext_vector_type(8)));
typedef float f32x4 __attribute__((ext_vector_type(4)));
typedef unsigned int uint;
typedef uint u32x2 __attribute__((ext_vector_type(2)));
typedef uint u32x4 __attribute__((ext_vector_type(4)));
typedef unsigned short u16x8 __attribute__((ext_vector_type(8)));

constexpr int NT = 4096;   // sequence length N
// H = 64, B = 2

__device__ __forceinline__ bf16x8 ld8f(const float* p) {
    f32x4 a = *(const f32x4*)p;
    f32x4 b = *(const f32x4*)(p + 4);
    bf16x8 v;
    v[0] = (bf16)a[0]; v[1] = (bf16)a[1]; v[2] = (bf16)a[2]; v[3] = (bf16)a[3];
    v[4] = (bf16)b[0]; v[5] = (bf16)b[1]; v[6] = (bf16)b[2]; v[7] = (bf16)b[3];
    return v;
}

__device__ __forceinline__ uint pack2(float a, float b) {
    unsigned short ua = __builtin_bit_cast(unsigned short, (bf16)a);
    unsigned short ub = __builtin_bit_cast(unsigned short, (bf16)b);
    return (uint)ua | ((uint)ub << 16);
}

__device__ __forceinline__ float bflo(uint w) { return __builtin_bit_cast(float, w << 16); }
__device__ __forceinline__ float bfhi(uint w) { return __builtin_bit_cast(float, w & 0xffff0000u); }

// ---------------------------------------------------------------------------
// Kernel 1: projections q_t = norm(h_t @ Wq[t]^T), k_e = norm(h_pred @ Wk[e]^T)
// (bf16 out), plus vT[p][b][h][n] = bf16 transpose of h_p.
// grid = 128 rowtiles x 3 slices.
// ---------------------------------------------------------------------------
__global__ __launch_bounds__(256) void prep_kernel(
    const float* __restrict__ h0, const float* __restrict__ h1, const float* __restrict__ h2,
    const float* __restrict__ Wq, const float* __restrict__ Wk,
    bf16* __restrict__ qn, bf16* __restrict__ kn, bf16* __restrict__ vT)
{
    __shared__ __align__(16) unsigned short tlds[4][16][72];
    const int tid = threadIdx.x, wid = tid >> 6, lane = tid & 63;
    const int l15 = lane & 15, quad = lane >> 4;
    const int bx = blockIdx.x;
    const int rt = bx & 127, sl = bx >> 7;       // slice 0..2
    const int g0 = rt * 64;
    const int grow = g0 + wid * 16 + l15;        // A-frag row (global b*N+n)
    const float* hs[3] = {h0, h1, h2};

    bf16x8 af[3][2];
#pragma unroll
    for (int p = 0; p < 3; p++)
#pragma unroll
        for (int hc = 0; hc < 2; hc++)
            af[p][hc] = ld8f(hs[p] + (size_t)grow * 64 + hc * 32 + quad * 8);

    if (sl == 0) {
        const int gr0 = g0 + wid * 16;
        const int bb = gr0 >> 12, n0 = gr0 & 4095;
#pragma unroll
        for (int p = 0; p < 3; p++) {
#pragma unroll
            for (int hc = 0; hc < 2; hc++)
                *(u16x8*)(&tlds[wid][l15][hc * 32 + quad * 8]) = __builtin_bit_cast(u16x8, af[p][hc]);
            unsigned short vals[16];
#pragma unroll
            for (int r = 0; r < 16; r++) vals[r] = tlds[wid][r][lane];
            uint us[8];
#pragma unroll
            for (int k = 0; k < 8; k++) us[k] = (uint)vals[2 * k] | ((uint)vals[2 * k + 1] << 16);
            uint* dst = (uint*)(vT + ((size_t)(p * 2 + bb) * 64 + lane) * NT + n0);
            u32x4 w0 = {us[0], us[1], us[2], us[3]};
            u32x4 w1 = {us[4], us[5], us[6], us[7]};
            *(u32x4*)dst = w0;
            *(u32x4*)(dst + 4) = w1;
        }
    }

    const int predmap[6] = {0, 2, 0, 1, 1, 2};
    const int pj0 = sl * 3;
#pragma unroll
    for (int pi = 0; pi < 3; pi++) {
        const int pj = pj0 + pi;
        const float* W = (pj < 3) ? (Wq + pj * 4096) : (Wk + (pj - 3) * 4096);
        const int src = (pj < 3) ? pj : predmap[pj - 3];
        bf16* outp = (pj < 3) ? (qn + (size_t)pj * 2 * NT * 64)
                              : (kn + (size_t)(pj - 3) * 2 * NT * 64);
        f32x4 s[4];
#pragma unroll
        for (int it = 0; it < 4; it++) {
            f32x4 acc = {0.f, 0.f, 0.f, 0.f};
#pragma unroll
            for (int hc = 0; hc < 2; hc++) {
                bf16x8 wb = ld8f(W + (size_t)(it * 16 + l15) * 64 + hc * 32 + quad * 8);
                acc = __builtin_amdgcn_mfma_f32_16x16x32_bf16(af[src][hc], wb, acc, 0, 0, 0);
            }
            s[it] = acc;
        }
#pragma unroll
        for (int r = 0; r < 4; r++) {
            float ss = s[0][r] * s[0][r] + s[1][r] * s[1][r] + s[2][r] * s[2][r] + s[3][r] * s[3][r];
            ss += __shfl_xor(ss, 1); ss += __shfl_xor(ss, 2);
            ss += __shfl_xor(ss, 4); ss += __shfl_xor(ss, 8);
            float rn = rsqrtf(ss);
            s[0][r] *= rn; s[1][r] *= rn; s[2][r] *= rn; s[3][r] *= rn;
        }
        const int rowbase = g0 + wid * 16 + quad * 4;
#pragma unroll
        for (int it = 0; it < 4; it++)
#pragma unroll
            for (int r = 0; r < 4; r++)
                outp[(size_t)(rowbase + r) * 64 + it * 16 + l15] = (bf16)s[it][r];
    }
}

// ---------------------------------------------------------------------------
// Kernel 1b: mask bit-pack + rowsums. Masks are exactly {0.0f, 1.0f}, so
// 1 bit is lossless and the rowsum is a popcount. One wave per (edge,row):
// lane l tests j = k*64+l per step; __ballot gives words 2k (lo) and 2k+1 (hi)
// of bits (bit index = j&31 in word j>>5 — matches attn's consumption).
// Pure coalesced stream: 403 MB read once at HBM rate; writes 12.6 MB.
// grid = 6*4096/4 = 6144 blocks (4 waves = 4 rows per block).
// ---------------------------------------------------------------------------
__global__ __launch_bounds__(256) void maskpack_kernel(
    const float* __restrict__ m00, const float* __restrict__ m20, const float* __restrict__ m01,
    const float* __restrict__ m11, const float* __restrict__ m12, const float* __restrict__ m22,
    uint* __restrict__ mbits, float* __restrict__ rs)
{
    const int wid = threadIdx.x >> 6, lane = threadIdx.x & 63;
    const int gr = blockIdx.x * 4 + wid;       // 0 .. 6*4096-1
    const int e = gr >> 12;
    const int row = gr & 4095;
    const float* masks[6] = {m00, m20, m01, m11, m12, m22};
    const float* __restrict__ mrow = masks[e] + (size_t)row * NT;
    uint* __restrict__ out = mbits + (size_t)gr * 128;

    uint w0own = 0, w1own = 0;
    int cnt = 0;
#pragma unroll 8
    for (int k = 0; k < 64; k++) {
        float v = mrow[k * 64 + lane];
        unsigned long long b = __ballot(v != 0.0f);
        cnt += __popcll(b);
        if (lane == k) { w0own = (uint)b; w1own = (uint)(b >> 32); }
    }
    u32x2 pr = {w0own, w1own};
    *(u32x2*)(out + 2 * lane) = pr;            // wave writes 512 B contiguous
    if (lane == 0) rs[gr] = (float)cnt;
}

// ---------------------------------------------------------------------------
// Kernel 2: masked cosine attention — R4 structure (LDS-staged K/V, unpinned
// K/V register prefetch, JC=4, launch_bounds(256,3) — NO sched_barrier pins:
// pinning forces ~64 regs live across compute -> scratch spill -> +400 MB
// traffic, proven rounds 5-7). Masks now come from the bit-packed array:
// 2 u32 per row per iter from L2/L3 instead of 32 KB/block-iter of HBM floats
// — removes the 403 MB HBM stream (and its latency) from this loop entirely.
// Partials: bf16 pairs in u32, layout [chunk][e][b][h/2][n], per-quad 64 B
// fully-coalesced stores. Rowsums come precomputed from maskpack.
// ---------------------------------------------------------------------------
template<int JC>
__global__ __launch_bounds__(256, 3) void attn_kernel(
    const bf16* __restrict__ qn, const bf16* __restrict__ kn, const bf16* __restrict__ vT,
    const uint* __restrict__ mbits, uint* __restrict__ Pacc)
{
    __shared__ __align__(16) bf16 Klds[2][64][72];
    __shared__ __align__(16) bf16 Vlds[2][64][72];
    const int tid = threadIdx.x, wid = tid >> 6, lane = tid & 63;
    const int l15 = lane & 15, quad = lane >> 4;
    const int bx = blockIdx.x;
    const int e = bx / (32 * JC);
    const int rem = bx % (32 * JC);
    const int qt = rem / JC, jcv = rem % JC;
    const int qrow0 = qt * 128, wstrip = wid * 32;
    const int qtypemap[6] = {0, 0, 1, 1, 2, 2};
    const int predmap[6]  = {0, 2, 0, 1, 1, 2};
    const int qtv = qtypemap[e], pv = predmap[e];
    constexpr int JSPAN = NT / JC;
    constexpr int NI = JSPAN / 64;
    const int jbeg = jcv * JSPAN;

    // per-thread staging line mapping (4 K lines + 4 V lines per thread)
    int s_b[4], s_jl[4], s_ch[4];
#pragma unroll
    for (int i = 0; i < 4; i++) {
        int u = tid + 256 * i;
        s_b[i] = u >> 9; s_jl[i] = (u >> 3) & 63; s_ch[i] = u & 7;
    }

    // Q fragments (stage-1 B-operand), register resident
    bf16x8 Qf[2][2][2];
#pragma unroll
    for (int b = 0; b < 2; b++)
#pragma unroll
        for (int mt = 0; mt < 2; mt++)
#pragma unroll
            for (int hc = 0; hc < 2; hc++)
                Qf[b][mt][hc] = *(const bf16x8*)(qn +
                    ((size_t)(qtv * 2 + b) * NT + qrow0 + wstrip + mt * 16 + l15) * 64 +
                    hc * 32 + quad * 8);

    f32x4 acc2[2][4][2];   // [b][ht][mt]  (acc^T: row=h, col=query)
#pragma unroll
    for (int b = 0; b < 2; b++)
#pragma unroll
        for (int ht = 0; ht < 4; ht++)
#pragma unroll
            for (int mt = 0; mt < 2; mt++) {
                f32x4 z = {0.f, 0.f, 0.f, 0.f};
                acc2[b][ht][mt] = z;
            }

    // mask-bit row pointers (this lane's two rows)
    const uint* mrowp[2];
#pragma unroll
    for (int mt = 0; mt < 2; mt++)
        mrowp[mt] = mbits + ((size_t)e * NT + qrow0 + wstrip + mt * 16 + l15) * 128;

    // ---- preload K/V staging regs for first iteration ----
    u32x4 kreg[4], vreg[4];
#pragma unroll
    for (int i = 0; i < 4; i++) {
        kreg[i] = *(const u32x4*)(kn + ((size_t)(e * 2 + s_b[i]) * NT + jbeg + s_jl[i]) * 64 + s_ch[i] * 8);
        vreg[i] = *(const u32x4*)(vT + ((size_t)(pv * 2 + s_b[i]) * 64 + s_jl[i]) * NT + jbeg + s_ch[i] * 8);
    }

#pragma unroll 1
    for (int ji = 0; ji < NI; ji++) {
        const int j0 = jbeg + ji * 64;
        const int jn = (ji + 1 < NI) ? (j0 + 64) : jbeg;   // next (clamped)

        // current iteration's mask bits (L2/L3-resident; latency covered by
        // the staging barriers below)
        u32x2 mw[2];
#pragma unroll
        for (int mt = 0; mt < 2; mt++)
            mw[mt] = *(const u32x2*)(mrowp[mt] + (j0 >> 5));

        __syncthreads();                           // prior compute done reading LDS
#pragma unroll
        for (int i = 0; i < 4; i++) {
            *(u32x4*)(&Klds[s_b[i]][s_jl[i]][s_ch[i] * 8]) = kreg[i];
            *(u32x4*)(&Vlds[s_b[i]][s_jl[i]][s_ch[i] * 8]) = vreg[i];
        }
        __syncthreads();                           // staged tile visible

        // issue next iteration's staging loads (unpinned — compiler schedules)
#pragma unroll
        for (int i = 0; i < 4; i++) {
            kreg[i] = *(const u32x4*)(kn + ((size_t)(e * 2 + s_b[i]) * NT + jn + s_jl[i]) * 64 + s_ch[i] * 8);
            vreg[i] = *(const u32x4*)(vT + ((size_t)(pv * 2 + s_b[i]) * 64 + s_jl[i]) * NT + jn + s_ch[i] * 8);
        }

        // expand bits -> float multipliers: jj = jt*16 + quad*4 + i
        // word = jt>>1, shift = (jt&1)*16 + quad*4 + i
        f32x4 mfv[2][4];
#pragma unroll
        for (int mt = 0; mt < 2; mt++)
#pragma unroll
            for (int jt = 0; jt < 4; jt++) {
                uint w = mw[mt][jt >> 1];
                uint nib = (w >> ((jt & 1) * 16 + quad * 4)) & 15u;
#pragma unroll
                for (int i = 0; i < 4; i++)
                    mfv[mt][jt][i] = (nib >> i) & 1u ? 1.0f : 0.0f;
            }

        // stage 1 for BOTH batches: S^T tiles, mask, pack bf16 pairs
        uint Pd[2][4][2][2];    // [b][jt][mt][d]
#pragma unroll
        for (int jt = 0; jt < 4; jt++)
#pragma unroll
            for (int b = 0; b < 2; b++)
#pragma unroll
                for (int mt = 0; mt < 2; mt++) {
                    f32x4 sc = {0.f, 0.f, 0.f, 0.f};
#pragma unroll
                    for (int hc = 0; hc < 2; hc++) {
                        bf16x8 a = *(const bf16x8*)(&Klds[b][jt * 16 + l15][hc * 32 + quad * 8]);
                        sc = __builtin_amdgcn_mfma_f32_16x16x32_bf16(a, Qf[b][mt][hc], sc, 0, 0, 0);
                    }
                    sc[0] *= mfv[mt][jt][0]; sc[1] *= mfv[mt][jt][1];
                    sc[2] *= mfv[mt][jt][2]; sc[3] *= mfv[mt][jt][3];
                    Pd[b][jt][mt][0] = pack2(sc[0], sc[1]);
                    Pd[b][jt][mt][1] = pack2(sc[2], sc[3]);
                }

        // stage 2 per batch: B-frags via ds_bpermute, then acc^T += VT·P^T
#pragma unroll
        for (int b = 0; b < 2; b++) {
            uint Bf[2][2][4];    // [mt][c][v]
#pragma unroll
            for (int mt = 0; mt < 2; mt++)
#pragma unroll
                for (int c = 0; c < 2; c++)
#pragma unroll
                    for (int v = 0; v < 4; v++) {
                        int srclane = ((((quad & 1) * 2 + (v >> 1)) * 16 + l15) << 2);
                        int lo = __builtin_amdgcn_ds_bpermute(srclane, (int)Pd[b][2 * c][mt][v & 1]);
                        int hi = __builtin_amdgcn_ds_bpermute(srclane, (int)Pd[b][2 * c + 1][mt][v & 1]);
                        Bf[mt][c][v] = (quad & 2) ? (uint)hi : (uint)lo;
                    }
#pragma unroll
            for (int ht = 0; ht < 4; ht++)
#pragma unroll
                for (int c = 0; c < 2; c++) {
                    bf16x8 a = *(const bf16x8*)(&Vlds[b][ht * 16 + l15][c * 32 + quad * 8]);
#pragma unroll
                    for (int mt = 0; mt < 2; mt++) {
                        u32x4 t = {Bf[mt][c][0], Bf[mt][c][1], Bf[mt][c][2], Bf[mt][c][3]};
                        bf16x8 bbv = __builtin_bit_cast(bf16x8, t);
                        acc2[b][ht][mt] =
                            __builtin_amdgcn_mfma_f32_16x16x32_bf16(a, bbv, acc2[b][ht][mt], 0, 0, 0);
                    }
                }
        }
    }

    // coalesced bf16-pair stores: Pacc[chunk][e][b][h2=h/2][n] (u32 words)
    // h = ht*16 + quad*4 + 2p + {0,1}  ->  h2 = ht*8 + quad*2 + p
#pragma unroll
    for (int b = 0; b < 2; b++)
#pragma unroll
        for (int ht = 0; ht < 4; ht++)
#pragma unroll
            for (int p = 0; p < 2; p++)
#pragma unroll
                for (int mt = 0; mt < 2; mt++) {
                    const int n = qrow0 + wstrip + mt * 16 + l15;
                    const int h2 = ht * 8 + quad * 2 + p;
                    Pacc[(((size_t)(jcv * 6 + e) * 2 + b) * 32 + h2) * NT + n] =
                        pack2(acc2[b][ht][mt][2 * p], acc2[b][ht][mt][2 * p + 1]);
                }
}

// ---------------------------------------------------------------------------
// Kernel 3: combine bf16-pair partials over JC chunks (acc_t = ΣP_e/rs_e),
// dt_t = 2*sigmoid(h_t Wdt_t^T + b) - 1, h_tn = h_t + step*dt*u_t, outputs.
// rs now comes whole-row from maskpack (no per-chunk sum).
// grid = 128 rowtiles x 3 types.
// ---------------------------------------------------------------------------
template<int JC>
__global__ __launch_bounds__(256) void update_kernel(
    const float* __restrict__ x0, const float* __restrict__ h0,
    const float* __restrict__ h1, const float* __restrict__ h2,
    const float* __restrict__ Wsu0, const float* __restrict__ Wsu12,
    const float* __restrict__ Wdt, const float* __restrict__ bdt,
    const float* __restrict__ stepp, const float* __restrict__ oscp,
    const uint* __restrict__ Pacc, const float* __restrict__ rs,
    float* __restrict__ dout)
{
    const int tid = threadIdx.x, wid = tid >> 6, lane = tid & 63;
    const int l15 = lane & 15, quad = lane >> 4;
    const int bx = blockIdx.x;
    const int rt = bx & 127, t = bx >> 7;
    const int g0 = rt * 64;
    const int grow = g0 + wid * 16 + l15;
    const int n = grow & 4095, bb = grow >> 12;
    const float step = *stepp, osc = *oscp;
    const float* hs[3] = {h0, h1, h2};
    const float* __restrict__ ht_base = hs[t];

    bf16x8 afh[2], afacc[2], afx;
#pragma unroll
    for (int hc = 0; hc < 2; hc++)
        afh[hc] = ld8f(ht_base + (size_t)grow * 64 + hc * 32 + quad * 8);
    if (t == 0) afx = ld8f(x0 + (size_t)grow * 32 + quad * 8);

    const float i0 = 1.f / rs[(size_t)(2 * t) * NT + n];
    const float i1 = 1.f / rs[(size_t)(2 * t + 1) * NT + n];
#pragma unroll
    for (int hc = 0; hc < 2; hc++) {
        float S0[8] = {0,0,0,0,0,0,0,0}, S1[8] = {0,0,0,0,0,0,0,0};
#pragma unroll
        for (int jc = 0; jc < JC; jc++) {
            const uint* b0 = Pacc + (((size_t)(jc * 6 + 2 * t) * 2 + bb) * 32) * NT + n;
            const uint* b1 = Pacc + (((size_t)(jc * 6 + 2 * t + 1) * 2 + bb) * 32) * NT + n;
#pragma unroll
            for (int jp = 0; jp < 4; jp++) {
                const int h2 = hc * 16 + quad * 4 + jp;
                uint w0 = b0[(size_t)h2 * NT];
                uint w1 = b1[(size_t)h2 * NT];
                S0[2 * jp]     += bflo(w0);
                S0[2 * jp + 1] += bfhi(w0);
                S1[2 * jp]     += bflo(w1);
                S1[2 * jp + 1] += bfhi(w1);
            }
        }
        bf16x8 v;
#pragma unroll
        for (int j = 0; j < 8; j++) v[j] = (bf16)(S0[j] * i0 + S1[j] * i1);
        afacc[hc] = v;
    }

    float bdtv[4];
#pragma unroll
    for (int it = 0; it < 4; it++)
        bdtv[it] = bdt[t * 64 + it * 16 + l15];

#pragma unroll
    for (int it = 0; it < 4; it++) {
        f32x4 z = {0.f, 0.f, 0.f, 0.f};
        f32x4 u = {0.f, 0.f, 0.f, 0.f};
#pragma unroll
        for (int hc = 0; hc < 2; hc++) {
            bf16x8 wb = ld8f(Wdt + (size_t)t * 4096 + (size_t)(it * 16 + l15) * 64 + hc * 32 + quad * 8);
            z = __builtin_amdgcn_mfma_f32_16x16x32_bf16(afh[hc], wb, z, 0, 0, 0);
        }
        if (t == 0) {
            bf16x8 w0 = ld8f(Wsu0 + (size_t)(it * 16 + l15) * 96 + quad * 8);
            u = __builtin_amdgcn_mfma_f32_16x16x32_bf16(afx, w0, u, 0, 0, 0);
#pragma unroll
            for (int kc = 0; kc < 2; kc++) {
                bf16x8 wk = ld8f(Wsu0 + (size_t)(it * 16 + l15) * 96 + 32 + kc * 32 + quad * 8);
                u = __builtin_amdgcn_mfma_f32_16x16x32_bf16(afacc[kc], wk, u, 0, 0, 0);
            }
        } else {
#pragma unroll
            for (int kc = 0; kc < 2; kc++) {
                bf16x8 wk = ld8f(Wsu12 + (size_t)(t - 1) * 4096 + (size_t)(it * 16 + l15) * 64 + kc * 32 + quad * 8);
                u = __builtin_amdgcn_mfma_f32_16x16x32_bf16(afacc[kc], wk, u, 0, 0, 0);
            }
        }
        const int colg = it * 16 + l15;
#pragma unroll
        for (int r = 0; r < 4; r++) {
            int row = g0 + wid * 16 + quad * 4 + r;
            float zz = z[r] + bdtv[it];
            float dtv = 2.f / (1.f + __expf(-zz)) - 1.f;
            float hval = ht_base[(size_t)row * 64 + colg];
            float hn = hval + step * dtv * u[r];
            dout[65536 + (size_t)t * 524288 + (size_t)row * 64 + colg] = hn;
            if (t == 2 && colg < 8)
                dout[(size_t)row * 8 + colg] = osc * hn;
        }
    }
}

extern "C" void kernel_launch(void* const* d_in, const int* in_sizes, int n_in,
                              void* d_out, int out_size, void* d_ws, size_t ws_size,
                              hipStream_t stream) {
    const float* x0   = (const float*)d_in[0];
    const float* h0   = (const float*)d_in[1];
    const float* h1   = (const float*)d_in[2];
    const float* h2   = (const float*)d_in[3];
    const float* m00  = (const float*)d_in[4];
    const float* m20  = (const float*)d_in[5];
    const float* m01  = (const float*)d_in[6];
    const float* m11  = (const float*)d_in[7];
    const float* m12  = (const float*)d_in[8];
    const float* m22  = (const float*)d_in[9];
    const float* Wq   = (const float*)d_in[10];
    const float* Wk   = (const float*)d_in[11];
    const float* Wsu0 = (const float*)d_in[12];
    const float* Wsu12= (const float*)d_in[13];
    const float* Wdt  = (const float*)d_in[14];
    const float* bdt  = (const float*)d_in[15];
    const float* step = (const float*)d_in[16];
    const float* oscl = (const float*)d_in[17];

    // workspace layout (element counts)
    bf16* qn  = (bf16*)d_ws;                    // 3*2*4096*64 = 1,572,864
    bf16* kn  = qn + 1572864;                   // 6*2*4096*64 = 3,145,728
    bf16* vT  = kn + 3145728;                   // 3*2*64*4096 = 1,572,864
    uint* mbits = (uint*)(vT + 1572864);        // 6*4096*128 = 3,145,728 u32 (12.6 MB)
    float* rs   = (float*)(mbits + 3145728);    // 6*4096 floats (98 KB)
    uint* Pacc  = (uint*)(rs + 24576);          // JC*6*2*32*4096 u32 (bf16 pairs)

    // bytes: 12,582,912 (bf16) + 12,582,912 (mbits) + 98,304 (rs) + JC*6,291,456
    auto need = [](size_t jc) { return 25264128 + jc * 6291456; };
    const int JC = (ws_size >= need(4)) ? 4 : ((ws_size >= need(2)) ? 2 : 1);

    prep_kernel<<<384, 256, 0, stream>>>(h0, h1, h2, Wq, Wk, qn, kn, vT);
    maskpack_kernel<<<6144, 256, 0, stream>>>(m00, m20, m01, m11, m12, m22, mbits, rs);

    if (JC == 4) {
        attn_kernel<4><<<6 * 32 * 4, 256, 0, stream>>>(qn, kn, vT, mbits, Pacc);
        update_kernel<4><<<384, 256, 0, stream>>>(x0, h0, h1, h2, Wsu0, Wsu12, Wdt, bdt,
                                                  step, oscl, Pacc, rs, (float*)d_out);
    } else if (JC == 2) {
        attn_kernel<2><<<6 * 32 * 2, 256, 0, stream>>>(qn, kn, vT, mbits, Pacc);
        update_kernel<2><<<384, 256, 0, stream>>>(x0, h0, h1, h2, Wsu0, Wsu12, Wdt, bdt,
                                                  step, oscl, Pacc, rs, (float*)d_out);
    } else {
        attn_kernel<1><<<6 * 32 * 1, 256, 0, stream>>>(qn, kn, vT, mbits, Pacc);
        update_kernel<1><<<384, 256, 0, stream>>>(x0, h0, h1, h2, Wsu0, Wsu12, Wdt, bdt,
                                                  step, oscl, Pacc, rs, (float*)d_out);
    }
}

// Round 9
// 509.031 us; speedup vs baseline: 1.2489x; 1.0200x over previous
//
#include <hip/hip_runtime.h>

typedef __bf16 bf16;
typedef bf16 bf16x8 __attribute__((ext_vector_type(8)));
typedef float f32x4 __attribute__((ext_vector_type(4)));
typedef unsigned int uint;
typedef uint u32x2 __attribute__((ext_vector_type(2)));
typedef uint u32x4 __attribute__((ext_vector_type(4)));
typedef unsigned short u16x8 __attribute__((ext_vector_type(8)));

constexpr int NT = 4096;   // sequence length N
// H = 64, B = 2

__device__ __forceinline__ bf16x8 ld8f(const float* p) {
    f32x4 a = *(const f32x4*)p;
    f32x4 b = *(const f32x4*)(p + 4);
    bf16x8 v;
    v[0] = (bf16)a[0]; v[1] = (bf16)a[1]; v[2] = (bf16)a[2]; v[3] = (bf16)a[3];
    v[4] = (bf16)b[0]; v[5] = (bf16)b[1]; v[6] = (bf16)b[2]; v[7] = (bf16)b[3];
    return v;
}

__device__ __forceinline__ uint pack2(float a, float b) {
    unsigned short ua = __builtin_bit_cast(unsigned short, (bf16)a);
    unsigned short ub = __builtin_bit_cast(unsigned short, (bf16)b);
    return (uint)ua | ((uint)ub << 16);
}

__device__ __forceinline__ float bflo(uint w) { return __builtin_bit_cast(float, w << 16); }
__device__ __forceinline__ float bfhi(uint w) { return __builtin_bit_cast(float, w & 0xffff0000u); }

// ---------------------------------------------------------------------------
// Kernel 1: projections q_t = norm(h_t @ Wq[t]^T), k_e = norm(h_pred @ Wk[e]^T)
// (bf16 out), plus vT[p][b][h][n] = bf16 transpose of h_p.
// grid = 128 rowtiles x 3 slices.
// ---------------------------------------------------------------------------
__global__ __launch_bounds__(256) void prep_kernel(
    const float* __restrict__ h0, const float* __restrict__ h1, const float* __restrict__ h2,
    const float* __restrict__ Wq, const float* __restrict__ Wk,
    bf16* __restrict__ qn, bf16* __restrict__ kn, bf16* __restrict__ vT)
{
    __shared__ __align__(16) unsigned short tlds[4][16][72];
    const int tid = threadIdx.x, wid = tid >> 6, lane = tid & 63;
    const int l15 = lane & 15, quad = lane >> 4;
    const int bx = blockIdx.x;
    const int rt = bx & 127, sl = bx >> 7;       // slice 0..2
    const int g0 = rt * 64;
    const int grow = g0 + wid * 16 + l15;        // A-frag row (global b*N+n)
    const float* hs[3] = {h0, h1, h2};

    bf16x8 af[3][2];
#pragma unroll
    for (int p = 0; p < 3; p++)
#pragma unroll
        for (int hc = 0; hc < 2; hc++)
            af[p][hc] = ld8f(hs[p] + (size_t)grow * 64 + hc * 32 + quad * 8);

    if (sl == 0) {
        const int gr0 = g0 + wid * 16;
        const int bb = gr0 >> 12, n0 = gr0 & 4095;
#pragma unroll
        for (int p = 0; p < 3; p++) {
#pragma unroll
            for (int hc = 0; hc < 2; hc++)
                *(u16x8*)(&tlds[wid][l15][hc * 32 + quad * 8]) = __builtin_bit_cast(u16x8, af[p][hc]);
            unsigned short vals[16];
#pragma unroll
            for (int r = 0; r < 16; r++) vals[r] = tlds[wid][r][lane];
            uint us[8];
#pragma unroll
            for (int k = 0; k < 8; k++) us[k] = (uint)vals[2 * k] | ((uint)vals[2 * k + 1] << 16);
            uint* dst = (uint*)(vT + ((size_t)(p * 2 + bb) * 64 + lane) * NT + n0);
            u32x4 w0 = {us[0], us[1], us[2], us[3]};
            u32x4 w1 = {us[4], us[5], us[6], us[7]};
            *(u32x4*)dst = w0;
            *(u32x4*)(dst + 4) = w1;
        }
    }

    const int predmap[6] = {0, 2, 0, 1, 1, 2};
    const int pj0 = sl * 3;
#pragma unroll
    for (int pi = 0; pi < 3; pi++) {
        const int pj = pj0 + pi;
        const float* W = (pj < 3) ? (Wq + pj * 4096) : (Wk + (pj - 3) * 4096);
        const int src = (pj < 3) ? pj : predmap[pj - 3];
        bf16* outp = (pj < 3) ? (qn + (size_t)pj * 2 * NT * 64)
                              : (kn + (size_t)(pj - 3) * 2 * NT * 64);
        f32x4 s[4];
#pragma unroll
        for (int it = 0; it < 4; it++) {
            f32x4 acc = {0.f, 0.f, 0.f, 0.f};
#pragma unroll
            for (int hc = 0; hc < 2; hc++) {
                bf16x8 wb = ld8f(W + (size_t)(it * 16 + l15) * 64 + hc * 32 + quad * 8);
                acc = __builtin_amdgcn_mfma_f32_16x16x32_bf16(af[src][hc], wb, acc, 0, 0, 0);
            }
            s[it] = acc;
        }
#pragma unroll
        for (int r = 0; r < 4; r++) {
            float ss = s[0][r] * s[0][r] + s[1][r] * s[1][r] + s[2][r] * s[2][r] + s[3][r] * s[3][r];
            ss += __shfl_xor(ss, 1); ss += __shfl_xor(ss, 2);
            ss += __shfl_xor(ss, 4); ss += __shfl_xor(ss, 8);
            float rn = rsqrtf(ss);
            s[0][r] *= rn; s[1][r] *= rn; s[2][r] *= rn; s[3][r] *= rn;
        }
        const int rowbase = g0 + wid * 16 + quad * 4;
#pragma unroll
        for (int it = 0; it < 4; it++)
#pragma unroll
            for (int r = 0; r < 4; r++)
                outp[(size_t)(rowbase + r) * 64 + it * 16 + l15] = (bf16)s[it][r];
    }
}

// ---------------------------------------------------------------------------
// Kernel 1b: mask bit-pack + rowsums, VECTORIZED. Masks are exactly {0,1}.
// One wave per (edge,row); per iteration each lane loads f32x4 (wave reads
// 1 KB coalesced), builds a 4-bit nibble for j = it*256 + lane*4 + i, and an
// 8-lane shfl_xor OR-reduce assembles u32 words with layout word[j>>5],
// bit j&31 (identical to what attn consumes; R8's scalar ballot version was
// correct but ran at 1.6 TB/s — 256 B/wave scalar loads). 16 fully-unrolled
// independent loads per row keep 16 KB in flight per wave.
// grid = 6*4096/4 blocks (4 waves = 4 rows per block).
// ---------------------------------------------------------------------------
__global__ __launch_bounds__(256) void maskpack_kernel(
    const float* __restrict__ m00, const float* __restrict__ m20, const float* __restrict__ m01,
    const float* __restrict__ m11, const float* __restrict__ m12, const float* __restrict__ m22,
    uint* __restrict__ mbits, float* __restrict__ rs)
{
    const int wid = threadIdx.x >> 6, lane = threadIdx.x & 63;
    const int gr = blockIdx.x * 4 + wid;       // 0 .. 6*4096-1
    const int e = gr >> 12;
    const int row = gr & 4095;
    const float* masks[6] = {m00, m20, m01, m11, m12, m22};
    const float* __restrict__ mrow = masks[e] + (size_t)row * NT;
    uint* __restrict__ out = mbits + (size_t)gr * 128;
    const int g8 = lane >> 3, sub = lane & 7;

    int cnt = 0;
#pragma unroll
    for (int it = 0; it < 16; it++) {
        f32x4 v = *(const f32x4*)(mrow + it * 256 + lane * 4);
        uint nib = (uint)(v[0] != 0.f) | ((uint)(v[1] != 0.f) << 1) |
                   ((uint)(v[2] != 0.f) << 2) | ((uint)(v[3] != 0.f) << 3);
        uint w = nib << (sub * 4);
        w |= __shfl_xor(w, 1);
        w |= __shfl_xor(w, 2);
        w |= __shfl_xor(w, 4);
        if (sub == 0) {
            out[it * 8 + g8] = w;              // 8 lanes -> 32 B contiguous
            cnt += __popc(w);
        }
    }
    // cnt nonzero only on lanes 0,8,...,56 — sum the 8 group leaders
    cnt += __shfl_xor(cnt, 8);
    cnt += __shfl_xor(cnt, 16);
    cnt += __shfl_xor(cnt, 32);
    if (lane == 0) rs[gr] = (float)cnt;
}

// ---------------------------------------------------------------------------
// Kernel 2: masked cosine attention — unchanged from R8 (est. ~85 us, near
// its DS-pipe floor): LDS-staged K/V, unpinned register prefetch, JC chunks,
// launch_bounds(256,3), bit-packed masks from L2/L3 (2 u32 per row per iter),
// bf16-pair partials [chunk][e][b][h/2][n] with 64 B coalesced stores.
// ---------------------------------------------------------------------------
template<int JC>
__global__ __launch_bounds__(256, 3) void attn_kernel(
    const bf16* __restrict__ qn, const bf16* __restrict__ kn, const bf16* __restrict__ vT,
    const uint* __restrict__ mbits, uint* __restrict__ Pacc)
{
    __shared__ __align__(16) bf16 Klds[2][64][72];
    __shared__ __align__(16) bf16 Vlds[2][64][72];
    const int tid = threadIdx.x, wid = tid >> 6, lane = tid & 63;
    const int l15 = lane & 15, quad = lane >> 4;
    const int bx = blockIdx.x;
    const int e = bx / (32 * JC);
    const int rem = bx % (32 * JC);
    const int qt = rem / JC, jcv = rem % JC;
    const int qrow0 = qt * 128, wstrip = wid * 32;
    const int qtypemap[6] = {0, 0, 1, 1, 2, 2};
    const int predmap[6]  = {0, 2, 0, 1, 1, 2};
    const int qtv = qtypemap[e], pv = predmap[e];
    constexpr int JSPAN = NT / JC;
    constexpr int NI = JSPAN / 64;
    const int jbeg = jcv * JSPAN;

    // per-thread staging line mapping (4 K lines + 4 V lines per thread)
    int s_b[4], s_jl[4], s_ch[4];
#pragma unroll
    for (int i = 0; i < 4; i++) {
        int u = tid + 256 * i;
        s_b[i] = u >> 9; s_jl[i] = (u >> 3) & 63; s_ch[i] = u & 7;
    }

    // Q fragments (stage-1 B-operand), register resident
    bf16x8 Qf[2][2][2];
#pragma unroll
    for (int b = 0; b < 2; b++)
#pragma unroll
        for (int mt = 0; mt < 2; mt++)
#pragma unroll
            for (int hc = 0; hc < 2; hc++)
                Qf[b][mt][hc] = *(const bf16x8*)(qn +
                    ((size_t)(qtv * 2 + b) * NT + qrow0 + wstrip + mt * 16 + l15) * 64 +
                    hc * 32 + quad * 8);

    f32x4 acc2[2][4][2];   // [b][ht][mt]  (acc^T: row=h, col=query)
#pragma unroll
    for (int b = 0; b < 2; b++)
#pragma unroll
        for (int ht = 0; ht < 4; ht++)
#pragma unroll
            for (int mt = 0; mt < 2; mt++) {
                f32x4 z = {0.f, 0.f, 0.f, 0.f};
                acc2[b][ht][mt] = z;
            }

    // mask-bit row pointers (this lane's two rows)
    const uint* mrowp[2];
#pragma unroll
    for (int mt = 0; mt < 2; mt++)
        mrowp[mt] = mbits + ((size_t)e * NT + qrow0 + wstrip + mt * 16 + l15) * 128;

    // ---- preload K/V staging regs for first iteration ----
    u32x4 kreg[4], vreg[4];
#pragma unroll
    for (int i = 0; i < 4; i++) {
        kreg[i] = *(const u32x4*)(kn + ((size_t)(e * 2 + s_b[i]) * NT + jbeg + s_jl[i]) * 64 + s_ch[i] * 8);
        vreg[i] = *(const u32x4*)(vT + ((size_t)(pv * 2 + s_b[i]) * 64 + s_jl[i]) * NT + jbeg + s_ch[i] * 8);
    }

#pragma unroll 1
    for (int ji = 0; ji < NI; ji++) {
        const int j0 = jbeg + ji * 64;
        const int jn = (ji + 1 < NI) ? (j0 + 64) : jbeg;   // next (clamped)

        // current iteration's mask bits (L2/L3-resident)
        u32x2 mw[2];
#pragma unroll
        for (int mt = 0; mt < 2; mt++)
            mw[mt] = *(const u32x2*)(mrowp[mt] + (j0 >> 5));

        __syncthreads();                           // prior compute done reading LDS
#pragma unroll
        for (int i = 0; i < 4; i++) {
            *(u32x4*)(&Klds[s_b[i]][s_jl[i]][s_ch[i] * 8]) = kreg[i];
            *(u32x4*)(&Vlds[s_b[i]][s_jl[i]][s_ch[i] * 8]) = vreg[i];
        }
        __syncthreads();                           // staged tile visible

        // issue next iteration's staging loads (unpinned — compiler schedules)
#pragma unroll
        for (int i = 0; i < 4; i++) {
            kreg[i] = *(const u32x4*)(kn + ((size_t)(e * 2 + s_b[i]) * NT + jn + s_jl[i]) * 64 + s_ch[i] * 8);
            vreg[i] = *(const u32x4*)(vT + ((size_t)(pv * 2 + s_b[i]) * 64 + s_jl[i]) * NT + jn + s_ch[i] * 8);
        }

        // expand bits -> float multipliers: jj = jt*16 + quad*4 + i
        f32x4 mfv[2][4];
#pragma unroll
        for (int mt = 0; mt < 2; mt++)
#pragma unroll
            for (int jt = 0; jt < 4; jt++) {
                uint w = mw[mt][jt >> 1];
                uint nib = (w >> ((jt & 1) * 16 + quad * 4)) & 15u;
#pragma unroll
                for (int i = 0; i < 4; i++)
                    mfv[mt][jt][i] = (nib >> i) & 1u ? 1.0f : 0.0f;
            }

        // stage 1 for BOTH batches: S^T tiles, mask, pack bf16 pairs
        uint Pd[2][4][2][2];    // [b][jt][mt][d]
#pragma unroll
        for (int jt = 0; jt < 4; jt++)
#pragma unroll
            for (int b = 0; b < 2; b++)
#pragma unroll
                for (int mt = 0; mt < 2; mt++) {
                    f32x4 sc = {0.f, 0.f, 0.f, 0.f};
#pragma unroll
                    for (int hc = 0; hc < 2; hc++) {
                        bf16x8 a = *(const bf16x8*)(&Klds[b][jt * 16 + l15][hc * 32 + quad * 8]);
                        sc = __builtin_amdgcn_mfma_f32_16x16x32_bf16(a, Qf[b][mt][hc], sc, 0, 0, 0);
                    }
                    sc[0] *= mfv[mt][jt][0]; sc[1] *= mfv[mt][jt][1];
                    sc[2] *= mfv[mt][jt][2]; sc[3] *= mfv[mt][jt][3];
                    Pd[b][jt][mt][0] = pack2(sc[0], sc[1]);
                    Pd[b][jt][mt][1] = pack2(sc[2], sc[3]);
                }

        // stage 2 per batch: B-frags via ds_bpermute, then acc^T += VT·P^T
#pragma unroll
        for (int b = 0; b < 2; b++) {
            uint Bf[2][2][4];    // [mt][c][v]
#pragma unroll
            for (int mt = 0; mt < 2; mt++)
#pragma unroll
                for (int c = 0; c < 2; c++)
#pragma unroll
                    for (int v = 0; v < 4; v++) {
                        int srclane = ((((quad & 1) * 2 + (v >> 1)) * 16 + l15) << 2);
                        int lo = __builtin_amdgcn_ds_bpermute(srclane, (int)Pd[b][2 * c][mt][v & 1]);
                        int hi = __builtin_amdgcn_ds_bpermute(srclane, (int)Pd[b][2 * c + 1][mt][v & 1]);
                        Bf[mt][c][v] = (quad & 2) ? (uint)hi : (uint)lo;
                    }
#pragma unroll
            for (int ht = 0; ht < 4; ht++)
#pragma unroll
                for (int c = 0; c < 2; c++) {
                    bf16x8 a = *(const bf16x8*)(&Vlds[b][ht * 16 + l15][c * 32 + quad * 8]);
#pragma unroll
                    for (int mt = 0; mt < 2; mt++) {
                        u32x4 t = {Bf[mt][c][0], Bf[mt][c][1], Bf[mt][c][2], Bf[mt][c][3]};
                        bf16x8 bbv = __builtin_bit_cast(bf16x8, t);
                        acc2[b][ht][mt] =
                            __builtin_amdgcn_mfma_f32_16x16x32_bf16(a, bbv, acc2[b][ht][mt], 0, 0, 0);
                    }
                }
        }
    }

    // coalesced bf16-pair stores: Pacc[chunk][e][b][h2=h/2][n] (u32 words)
#pragma unroll
    for (int b = 0; b < 2; b++)
#pragma unroll
        for (int ht = 0; ht < 4; ht++)
#pragma unroll
            for (int p = 0; p < 2; p++)
#pragma unroll
                for (int mt = 0; mt < 2; mt++) {
                    const int n = qrow0 + wstrip + mt * 16 + l15;
                    const int h2 = ht * 8 + quad * 2 + p;
                    Pacc[(((size_t)(jcv * 6 + e) * 2 + b) * 32 + h2) * NT + n] =
                        pack2(acc2[b][ht][mt][2 * p], acc2[b][ht][mt][2 * p + 1]);
                }
}

// ---------------------------------------------------------------------------
// Kernel 3: combine bf16-pair partials over JC chunks (acc_t = ΣP_e/rs_e),
// dt_t = 2*sigmoid(h_t Wdt_t^T + b) - 1, h_tn = h_t + step*dt*u_t, outputs.
// grid = 128 rowtiles x 3 types.
// ---------------------------------------------------------------------------
template<int JC>
__global__ __launch_bounds__(256) void update_kernel(
    const float* __restrict__ x0, const float* __restrict__ h0,
    const float* __restrict__ h1, const float* __restrict__ h2,
    const float* __restrict__ Wsu0, const float* __restrict__ Wsu12,
    const float* __restrict__ Wdt, const float* __restrict__ bdt,
    const float* __restrict__ stepp, const float* __restrict__ oscp,
    const uint* __restrict__ Pacc, const float* __restrict__ rs,
    float* __restrict__ dout)
{
    const int tid = threadIdx.x, wid = tid >> 6, lane = tid & 63;
    const int l15 = lane & 15, quad = lane >> 4;
    const int bx = blockIdx.x;
    const int rt = bx & 127, t = bx >> 7;
    const int g0 = rt * 64;
    const int grow = g0 + wid * 16 + l15;
    const int n = grow & 4095, bb = grow >> 12;
    const float step = *stepp, osc = *oscp;
    const float* hs[3] = {h0, h1, h2};
    const float* __restrict__ ht_base = hs[t];

    bf16x8 afh[2], afacc[2], afx;
#pragma unroll
    for (int hc = 0; hc < 2; hc++)
        afh[hc] = ld8f(ht_base + (size_t)grow * 64 + hc * 32 + quad * 8);
    if (t == 0) afx = ld8f(x0 + (size_t)grow * 32 + quad * 8);

    const float i0 = 1.f / rs[(size_t)(2 * t) * NT + n];
    const float i1 = 1.f / rs[(size_t)(2 * t + 1) * NT + n];
#pragma unroll
    for (int hc = 0; hc < 2; hc++) {
        float S0[8] = {0,0,0,0,0,0,0,0}, S1[8] = {0,0,0,0,0,0,0,0};
#pragma unroll
        for (int jc = 0; jc < JC; jc++) {
            const uint* b0 = Pacc + (((size_t)(jc * 6 + 2 * t) * 2 + bb) * 32) * NT + n;
            const uint* b1 = Pacc + (((size_t)(jc * 6 + 2 * t + 1) * 2 + bb) * 32) * NT + n;
#pragma unroll
            for (int jp = 0; jp < 4; jp++) {
                const int h2 = hc * 16 + quad * 4 + jp;
                uint w0 = b0[(size_t)h2 * NT];
                uint w1 = b1[(size_t)h2 * NT];
                S0[2 * jp]     += bflo(w0);
                S0[2 * jp + 1] += bfhi(w0);
                S1[2 * jp]     += bflo(w1);
                S1[2 * jp + 1] += bfhi(w1);
            }
        }
        bf16x8 v;
#pragma unroll
        for (int j = 0; j < 8; j++) v[j] = (bf16)(S0[j] * i0 + S1[j] * i1);
        afacc[hc] = v;
    }

    float bdtv[4];
#pragma unroll
    for (int it = 0; it < 4; it++)
        bdtv[it] = bdt[t * 64 + it * 16 + l15];

#pragma unroll
    for (int it = 0; it < 4; it++) {
        f32x4 z = {0.f, 0.f, 0.f, 0.f};
        f32x4 u = {0.f, 0.f, 0.f, 0.f};
#pragma unroll
        for (int hc = 0; hc < 2; hc++) {
            bf16x8 wb = ld8f(Wdt + (size_t)t * 4096 + (size_t)(it * 16 + l15) * 64 + hc * 32 + quad * 8);
            z = __builtin_amdgcn_mfma_f32_16x16x32_bf16(afh[hc], wb, z, 0, 0, 0);
        }
        if (t == 0) {
            bf16x8 w0 = ld8f(Wsu0 + (size_t)(it * 16 + l15) * 96 + quad * 8);
            u = __builtin_amdgcn_mfma_f32_16x16x32_bf16(afx, w0, u, 0, 0, 0);
#pragma unroll
            for (int kc = 0; kc < 2; kc++) {
                bf16x8 wk = ld8f(Wsu0 + (size_t)(it * 16 + l15) * 96 + 32 + kc * 32 + quad * 8);
                u = __builtin_amdgcn_mfma_f32_16x16x32_bf16(afacc[kc], wk, u, 0, 0, 0);
            }
        } else {
#pragma unroll
            for (int kc = 0; kc < 2; kc++) {
                bf16x8 wk = ld8f(Wsu12 + (size_t)(t - 1) * 4096 + (size_t)(it * 16 + l15) * 64 + kc * 32 + quad * 8);
                u = __builtin_amdgcn_mfma_f32_16x16x32_bf16(afacc[kc], wk, u, 0, 0, 0);
            }
        }
        const int colg = it * 16 + l15;
#pragma unroll
        for (int r = 0; r < 4; r++) {
            int row = g0 + wid * 16 + quad * 4 + r;
            float zz = z[r] + bdtv[it];
            float dtv = 2.f / (1.f + __expf(-zz)) - 1.f;
            float hval = ht_base[(size_t)row * 64 + colg];
            float hn = hval + step * dtv * u[r];
            dout[65536 + (size_t)t * 524288 + (size_t)row * 64 + colg] = hn;
            if (t == 2 && colg < 8)
                dout[(size_t)row * 8 + colg] = osc * hn;
        }
    }
}

extern "C" void kernel_launch(void* const* d_in, const int* in_sizes, int n_in,
                              void* d_out, int out_size, void* d_ws, size_t ws_size,
                              hipStream_t stream) {
    const float* x0   = (const float*)d_in[0];
    const float* h0   = (const float*)d_in[1];
    const float* h1   = (const float*)d_in[2];
    const float* h2   = (const float*)d_in[3];
    const float* m00  = (const float*)d_in[4];
    const float* m20  = (const float*)d_in[5];
    const float* m01  = (const float*)d_in[6];
    const float* m11  = (const float*)d_in[7];
    const float* m12  = (const float*)d_in[8];
    const float* m22  = (const float*)d_in[9];
    const float* Wq   = (const float*)d_in[10];
    const float* Wk   = (const float*)d_in[11];
    const float* Wsu0 = (const float*)d_in[12];
    const float* Wsu12= (const float*)d_in[13];
    const float* Wdt  = (const float*)d_in[14];
    const float* bdt  = (const float*)d_in[15];
    const float* step = (const float*)d_in[16];
    const float* oscl = (const float*)d_in[17];

    // workspace layout (element counts)
    bf16* qn  = (bf16*)d_ws;                    // 3*2*4096*64 = 1,572,864
    bf16* kn  = qn + 1572864;                   // 6*2*4096*64 = 3,145,728
    bf16* vT  = kn + 3145728;                   // 3*2*64*4096 = 1,572,864
    uint* mbits = (uint*)(vT + 1572864);        // 6*4096*128 = 3,145,728 u32 (12.6 MB)
    float* rs   = (float*)(mbits + 3145728);    // 6*4096 floats (98 KB)
    uint* Pacc  = (uint*)(rs + 24576);          // JC*6*2*32*4096 u32 (bf16 pairs)

    // bytes: 12,582,912 (bf16) + 12,582,912 (mbits) + 98,304 (rs) + JC*6,291,456
    auto need = [](size_t jc) { return 25264128 + jc * 6291456; };
    const int JC = (ws_size >= need(4)) ? 4 : ((ws_size >= need(2)) ? 2 : 1);

    prep_kernel<<<384, 256, 0, stream>>>(h0, h1, h2, Wq, Wk, qn, kn, vT);
    maskpack_kernel<<<6144, 256, 0, stream>>>(m00, m20, m01, m11, m12, m22, mbits, rs);

    if (JC == 4) {
        attn_kernel<4><<<6 * 32 * 4, 256, 0, stream>>>(qn, kn, vT, mbits, Pacc);
        update_kernel<4><<<384, 256, 0, stream>>>(x0, h0, h1, h2, Wsu0, Wsu12, Wdt, bdt,
                                                  step, oscl, Pacc, rs, (float*)d_out);
    } else if (JC == 2) {
        attn_kernel<2><<<6 * 32 * 2, 256, 0, stream>>>(qn, kn, vT, mbits, Pacc);
        update_kernel<2><<<384, 256, 0, stream>>>(x0, h0, h1, h2, Wsu0, Wsu12, Wdt, bdt,
                                                  step, oscl, Pacc, rs, (float*)d_out);
    } else {
        attn_kernel<1><<<6 * 32 * 1, 256, 0, stream>>>(qn, kn, vT, mbits, Pacc);
        update_kernel<1><<<384, 256, 0, stream>>>(x0, h0, h1, h2, Wsu0, Wsu12, Wdt, bdt,
                                                  step, oscl, Pacc, rs, (float*)d_out);
    }
}